// Round 5
// baseline (316.142 us; speedup 1.0000x reference)
//
#include <hip/hip_runtime.h>
#include <hip/hip_cooperative_groups.h>
#include <hip/hip_fp16.h>
#include <math.h>

#define B_ 1024
#define F_ 39
#define K_ 16
#define P_ 741
#define T_ 9139
#define NC_ 9880          // P_ + T_
#define EPS_ 1e-3f
#define YSTR 24           // Y row stride in f16 (48 B)
#define ESTR 40           // emb row stride in f16 (80 B: b128 slot=(5c)%8, 5 coprime 8)
#define LS2 9920          // levels row stride in f16 elems (19840 B, 16B-aligned)
#define NSPLIT 32         // stats partial splits (32 rows each)
#define NBLK 512          // cooperative grid: 2 blocks/CU on 256 CUs
#define NTHR 512

namespace cg = cooperative_groups;

typedef _Float16 half2v __attribute__((ext_vector_type(2)));

__device__ __forceinline__ float hdot2(unsigned a, unsigned b, float acc) {
    half2v ha = __builtin_bit_cast(half2v, a);
    half2v hb = __builtin_bit_cast(half2v, b);
#if __has_builtin(__builtin_amdgcn_fdot2)
    return __builtin_amdgcn_fdot2(ha, hb, acc, false);
#else
    return acc + (float)ha.x * (float)hb.x + (float)ha.y * (float)hb.y;
#endif
}

// ---------------- single cooperative kernel: 4 phases, 3 grid syncs ----------------
// Resources per block: 512 thr (8 waves), LDS 40.9 KB, VGPR capped 128 by
// __launch_bounds__(512,4)  ->  2 blocks/CU guaranteed co-resident (512 blocks total).
__global__ __launch_bounds__(NTHR, 4) void fused_k(
        const int* __restrict__ feats, const float* __restrict__ w,
        const float* __restrict__ v, const float* __restrict__ bias,
        const float* __restrict__ gamma2, const float* __restrict__ beta2,
        const float* __restrict__ gw2, const float* __restrict__ gamma3,
        const float* __restrict__ beta3, const float* __restrict__ gw3,
        const int* __restrict__ rows, const int* __restrict__ cols,
        const int* __restrict__ i1, const int* __restrict__ i2,
        const int* __restrict__ i3, float* __restrict__ scale,
        float* __restrict__ psum, float* __restrict__ psumsq,
        float* __restrict__ Cacc, unsigned short* __restrict__ levels,
        float* __restrict__ out) {
    cg::grid_group grid = cg::this_grid();
    int blk = blockIdx.x, tid = threadIdx.x;
    __shared__ int tok[F_];
    __shared__ __attribute__((aligned(16))) unsigned short emb2[F_ * ESTR];   // 3120 B
    __shared__ __attribute__((aligned(16))) unsigned short Y2[P_ * YSTR];     // 35568 B
    __shared__ float red[NTHR];                                               // 2048 B

    if (blk == 0 && tid == 0) Cacc[0] = 0.f;

    // ================= phase L: levels for rows 2*blk, 2*blk+1 ======================
    for (int rr = 0; rr < 2; ++rr) {
        int b = blk * 2 + rr;
        unsigned short* lrow = levels + (size_t)b * LS2;
        if (tid < F_) tok[tid] = feats[b * F_ + tid];
        __syncthreads();
        for (int idx = tid; idx < F_ * K_; idx += NTHR) {
            int f = idx >> 4, k = idx & 15;
            emb2[f * ESTR + k] = __builtin_bit_cast(unsigned short,
                                     __float2half(v[(size_t)tok[f] * K_ + k]));
        }
        __syncthreads();

        // P0: 741 pair products -> Y2 (f16) + level2 -> global
#pragma unroll 1
        for (int pp = 0; pp < 2; ++pp) {
            int p = pp * NTHR + tid;
            if (p < P_) {
                int o1 = cols[p] * ESTR;
                int o2 = rows[p] * ESTR;
                uint4 ua0 = *(const uint4*)&emb2[o1];
                uint4 ua1 = *(const uint4*)&emb2[o1 + 8];
                uint4 uc0 = *(const uint4*)&emb2[o2];
                uint4 uc1 = *(const uint4*)&emb2[o2 + 8];
                float s = 0.f;
                uint4 y0, y1;
#define PKMUL(dst, a, c) {                                                    \
                half2v _a = __builtin_bit_cast(half2v, a);                    \
                half2v _c = __builtin_bit_cast(half2v, c);                    \
                half2v _y = _a * _c;                                          \
                dst = __builtin_bit_cast(unsigned, _y);                       \
                s = hdot2(a, c, s); }
                PKMUL(y0.x, ua0.x, uc0.x); PKMUL(y0.y, ua0.y, uc0.y);
                PKMUL(y0.z, ua0.z, uc0.z); PKMUL(y0.w, ua0.w, uc0.w);
                PKMUL(y1.x, ua1.x, uc1.x); PKMUL(y1.y, ua1.y, uc1.y);
                PKMUL(y1.z, ua1.z, uc1.z); PKMUL(y1.w, ua1.w, uc1.w);
#undef PKMUL
                *(uint4*)&Y2[p * YSTR] = y0;
                *(uint4*)&Y2[p * YSTR + 8] = y1;
                lrow[p] = __builtin_bit_cast(unsigned short, __float2half(s));
            }
        }
        __syncthreads();

        // P1: triples with inline index math (no descriptor array -> no scratch)
#pragma unroll 3
        for (int i = 0; i < 18; ++i) {
            int t = i * NTHR + tid;
            if (t < T_) {
                int a = i1[t], bb = i2[t], c3 = i3[t];
                int p = a * (2 * F_ - 1 - a) / 2 + (bb - a - 1);  // lex pair idx (a,bb)
                int yb = p * YSTR;
                int o3 = c3 * ESTR;
                uint4 uy0 = *(const uint4*)&Y2[yb];
                uint4 uy1 = *(const uint4*)&Y2[yb + 8];
                uint4 ue0 = *(const uint4*)&emb2[o3];
                uint4 ue1 = *(const uint4*)&emb2[o3 + 8];
                float s = 0.f;
                s = hdot2(uy0.x, ue0.x, s); s = hdot2(uy0.y, ue0.y, s);
                s = hdot2(uy0.z, ue0.z, s); s = hdot2(uy0.w, ue0.w, s);
                s = hdot2(uy1.x, ue1.x, s); s = hdot2(uy1.y, ue1.y, s);
                s = hdot2(uy1.z, ue1.z, s); s = hdot2(uy1.w, ue1.w, s);
                lrow[P_ + t] = __builtin_bit_cast(unsigned short, __float2half(s));
            }
        }
        __syncthreads();   // protect tok/emb2/Y2 before next row overwrites
    }
    grid.sync();

    // ================= phase S: column partial stats (NSPLIT x NC/2) ================
    {
        int gid = blk * NTHR + tid;
        if (gid < NSPLIT * (NC_ / 2)) {
            int col2 = gid % (NC_ / 2);
            int sy   = gid / (NC_ / 2);
            const unsigned* p = (const unsigned*)levels
                              + (size_t)(sy * (B_ / NSPLIT)) * (LS2 / 2) + col2;
            float s0 = 0.f, s1 = 0.f, q0 = 0.f, q1 = 0.f;
            float s2 = 0.f, s3 = 0.f, q2 = 0.f, q3 = 0.f;
#pragma unroll
            for (int r = 0; r < B_ / NSPLIT; r += 4) {
                unsigned u0 = p[(size_t)(r + 0) * (LS2 / 2)];
                unsigned u1 = p[(size_t)(r + 1) * (LS2 / 2)];
                unsigned u2 = p[(size_t)(r + 2) * (LS2 / 2)];
                unsigned u3 = p[(size_t)(r + 3) * (LS2 / 2)];
                float2 f0 = __half22float2(__builtin_bit_cast(__half2, u0));
                float2 f1 = __half22float2(__builtin_bit_cast(__half2, u1));
                float2 f2 = __half22float2(__builtin_bit_cast(__half2, u2));
                float2 f3 = __half22float2(__builtin_bit_cast(__half2, u3));
                s0 += f0.x; q0 += f0.x * f0.x; s1 += f0.y; q1 += f0.y * f0.y;
                s2 += f1.x; q2 += f1.x * f1.x; s3 += f1.y; q3 += f1.y * f1.y;
                s0 += f2.x; q0 += f2.x * f2.x; s1 += f2.y; q1 += f2.y * f2.y;
                s2 += f3.x; q2 += f3.x * f3.x; s3 += f3.y; q3 += f3.y * f3.y;
            }
            float2 sv; sv.x = s0 + s2; sv.y = s1 + s3;
            float2 qv; qv.x = q0 + q2; qv.y = q1 + q3;
            ((float2*)psum)[(size_t)sy * (NC_ / 2) + col2]   = sv;
            ((float2*)psumsq)[(size_t)sy * (NC_ / 2) + col2] = qv;
        }
    }
    grid.sync();

    // ================= phase F: BN finalize -> scale + scalar C =====================
    {
        int col = blk * NTHR + tid;
        if (blk * NTHR < NC_) {                       // blocks 0..19 participate
            float c = 0.f;
            if (col < NC_) {
                float s1 = 0.f, s2 = 0.f;
#pragma unroll 8
                for (int sy = 0; sy < NSPLIT; ++sy) {
                    s1 += psum[(size_t)sy * NC_ + col];
                    s2 += psumsq[(size_t)sy * NC_ + col];
                }
                float mean = s1 * (1.0f / B_);
                float var  = s2 * (1.0f / B_) - mean * mean;
                float inv  = 1.0f / sqrtf(var + EPS_);
                float g, be, gw;
                if (col < P_) {
                    g = gamma2[col]; be = beta2[col]; gw = gw2[col];
                } else {
                    int t = col - P_;
                    g = gamma3[t]; be = beta3[t]; gw = gw3[t];
                }
                scale[col] = gw * g * inv;
                c = gw * (be - g * inv * mean);
            }
            red[tid] = c;
            __syncthreads();
            for (int s = 256; s > 0; s >>= 1) {
                if (tid < s) red[tid] += red[tid + s];
                __syncthreads();
            }
            if (tid == 0) atomicAdd(Cacc, red[0]);
        }
    }
    grid.sync();

    // ================= phase O: weighted row sums -> logits =========================
    {
        float Cv = Cacc[0] + bias[0];
        for (int rr = 0; rr < 2; ++rr) {
            int b = blk * 2 + rr;
            const uint4* lv = (const uint4*)(levels + (size_t)b * LS2);
            float acc = 0.f;
            // 9880 f16 = 1235 uint4 exactly; 512 threads -> 3 strided iterations
#pragma unroll
            for (int it = 0; it < 3; ++it) {
                int idx = it * NTHR + tid;
                if (idx < 1235) {
                    uint4 u = lv[idx];
                    float4 sa = *(const float4*)&scale[idx * 8];
                    float4 sb = *(const float4*)&scale[idx * 8 + 4];
                    float2 f0 = __half22float2(__builtin_bit_cast(__half2, u.x));
                    float2 f1 = __half22float2(__builtin_bit_cast(__half2, u.y));
                    float2 f2 = __half22float2(__builtin_bit_cast(__half2, u.z));
                    float2 f3 = __half22float2(__builtin_bit_cast(__half2, u.w));
                    acc += sa.x * f0.x + sa.y * f0.y + sa.z * f1.x + sa.w * f1.y;
                    acc += sb.x * f2.x + sb.y * f2.y + sb.z * f3.x + sb.w * f3.y;
                }
            }
            if (tid < F_) acc += w[feats[b * F_ + tid]];   // linear term
            __syncthreads();                               // red[] reuse hygiene
            red[tid] = acc;
            __syncthreads();
            for (int s = 256; s > 0; s >>= 1) {
                if (tid < s) red[tid] += red[tid + s];
                __syncthreads();
            }
            if (tid == 0) out[b] = red[0] + Cv;
        }
    }
}

// ---------- host launcher -----------------------------------------------------------
extern "C" void kernel_launch(void* const* d_in, const int* in_sizes, int n_in,
                              void* d_out, int out_size, void* d_ws, size_t ws_size,
                              hipStream_t stream) {
    const int*   feats  = (const int*)d_in[0];
    const float* w      = (const float*)d_in[1];
    const float* v      = (const float*)d_in[2];
    const float* bias   = (const float*)d_in[3];
    const float* gamma2 = (const float*)d_in[4];
    const float* beta2  = (const float*)d_in[5];
    const float* gw2    = (const float*)d_in[6];
    const float* gamma3 = (const float*)d_in[7];
    const float* beta3  = (const float*)d_in[8];
    const float* gw3    = (const float*)d_in[9];
    const int*   rows   = (const int*)d_in[10];
    const int*   cols   = (const int*)d_in[11];
    const int*   i1     = (const int*)d_in[12];
    const int*   i2     = (const int*)d_in[13];
    const int*   i3     = (const int*)d_in[14];
    float*       out    = (float*)d_out;
    float*       ws     = (float*)d_ws;

    // workspace layout (float offsets)
    float*          scale  = ws;                               // 9880
    float*          psum   = ws + 9880;                        // 32*9880 = 316160
    float*          psumsq = ws + 326040;                      // 316160
    float*          Cacc   = ws + 642200;                      // 1 (+ pad)
    unsigned short* levels = (unsigned short*)(ws + 642304);   // 1024*9920 f16 (~20.3 MB)

    void* args[] = {
        (void*)&feats, (void*)&w, (void*)&v, (void*)&bias,
        (void*)&gamma2, (void*)&beta2, (void*)&gw2,
        (void*)&gamma3, (void*)&beta3, (void*)&gw3,
        (void*)&rows, (void*)&cols, (void*)&i1, (void*)&i2, (void*)&i3,
        (void*)&scale, (void*)&psum, (void*)&psumsq, (void*)&Cacc,
        (void*)&levels, (void*)&out
    };
    hipLaunchCooperativeKernel((const void*)fused_k, dim3(NBLK), dim3(NTHR),
                               args, 0, stream);
}

// Round 6
// 123.462 us; speedup vs baseline: 2.5606x; 2.5606x over previous
//
#include <hip/hip_runtime.h>
#include <hip/hip_fp16.h>
#include <math.h>

#define B_ 1024
#define F_ 39
#define K_ 16
#define P_ 741
#define T_ 9139
#define NC_ 9880          // P_ + T_
#define EPS_ 1e-3f
#define YSTR 24           // Y row stride in f16 (48 B: 16B-aligned rows)
#define ESTR 40           // emb row stride in f16 (80 B: b128 slot=(5c)%8, 5 coprime 8)
#define LS2 9920          // levels row stride in f16 elems (19840 B, 16B-aligned)
#define NSPLIT 8          // stats partial splits (128 rows each)

typedef _Float16 half2v __attribute__((ext_vector_type(2)));

__device__ __forceinline__ float hdot2(unsigned a, unsigned b, float acc) {
    half2v ha = __builtin_bit_cast(half2v, a);
    half2v hb = __builtin_bit_cast(half2v, b);
#if __has_builtin(__builtin_amdgcn_fdot2)
    return __builtin_amdgcn_fdot2(ha, hb, acc, false);
#else
    return acc + (float)ha.x * (float)hb.x + (float)ha.y * (float)hb.y;
#endif
}
__device__ __forceinline__ float f16f(unsigned short h) {
    return __half2float(__builtin_bit_cast(__half, h));
}

// ---------- kernel 0: zero Cacc + pack column indices -------------------------------
// pairs  (c < P_):  pk = (cols[c]*ESTR) | (rows[c]*ESTR)<<11    (each <= 1520, 11 bits)
// triples(c >= P_): pk = (pair_idx*YSTR) | (i3*ESTR)<<15        (17760 fits 15 bits)
__global__ __launch_bounds__(256) void prep_k(const int* __restrict__ rows,
                                              const int* __restrict__ cols,
                                              const int* __restrict__ i1,
                                              const int* __restrict__ i2,
                                              const int* __restrict__ i3,
                                              unsigned* __restrict__ pidx,
                                              float* __restrict__ Cacc) {
    int c = blockIdx.x * 256 + threadIdx.x;
    if (c >= NC_) return;
    if (c == 0) Cacc[0] = 0.f;
    unsigned pk;
    if (c < P_) {
        pk = (unsigned)(cols[c] * ESTR) | ((unsigned)(rows[c] * ESTR) << 11);
    } else {
        int t = c - P_;
        int a = i1[t], b = i2[t], cc = i3[t];
        int p = a * (2 * F_ - 1 - a) / 2 + (b - a - 1);   // lex pair index of (a,b)
        pk = (unsigned)(p * YSTR) | ((unsigned)(cc * ESTR) << 15);
    }
    pidx[c] = pk;
}

// ---------- kernel 1: fused gather + pair products + all level values (f16) ---------
// One batch row per block; 1024 blocks x 512 threads; ~39 KB LDS -> 4 blocks/CU.
__global__ __launch_bounds__(512) void levels_k(const int* __restrict__ feats,
                                                const float* __restrict__ v,
                                                const unsigned* __restrict__ pidx,
                                                unsigned short* __restrict__ levels) {
    int b = blockIdx.x;
    int tid = threadIdx.x;
    __shared__ int tok[F_];
    __shared__ __attribute__((aligned(16))) unsigned short emb2[F_ * ESTR];   // 3120 B
    __shared__ __attribute__((aligned(16))) unsigned short Y2[P_ * YSTR];     // 35568 B

    unsigned short* lrow = levels + (size_t)b * LS2;

    // prefetch all column descriptors this thread will need (loads overlap staging/P0)
    unsigned pk_p0 = (tid < P_) ? pidx[tid] : 0u;
    unsigned pk_p1 = (tid + 512 < P_) ? pidx[tid + 512] : 0u;
    unsigned pkt[18];
#pragma unroll
    for (int i = 0; i < 18; ++i) {
        int t = i * 512 + tid;
        pkt[i] = (t < T_) ? pidx[P_ + t] : 0u;
    }

    if (tid < F_) tok[tid] = feats[b * F_ + tid];
    __syncthreads();
    for (int idx = tid; idx < F_ * K_; idx += 512) {
        int f = idx >> 4, k = idx & 15;
        emb2[f * ESTR + k] = __builtin_bit_cast(unsigned short,
                                 __float2half(v[(size_t)tok[f] * K_ + k]));
    }
    __syncthreads();

    // P0: all 741 pair products -> Y2 (f16), level2 -> global
#pragma unroll 1
    for (int pp = 0; pp < 2; ++pp) {
        int p = pp * 512 + tid;
        if (p < P_) {
            unsigned pk = pp == 0 ? pk_p0 : pk_p1;
            int o1 = (int)(pk & 2047u);
            int o2 = (int)((pk >> 11) & 2047u);
            uint4 ua0 = *(const uint4*)&emb2[o1];
            uint4 ua1 = *(const uint4*)&emb2[o1 + 8];
            uint4 uc0 = *(const uint4*)&emb2[o2];
            uint4 uc1 = *(const uint4*)&emb2[o2 + 8];
            float s = 0.f;
            uint4 y0, y1;
#define PKMUL(dst, a, c) {                                                    \
            half2v _a = __builtin_bit_cast(half2v, a);                        \
            half2v _c = __builtin_bit_cast(half2v, c);                        \
            half2v _y = _a * _c;                                              \
            dst = __builtin_bit_cast(unsigned, _y);                           \
            s = hdot2(a, c, s); }
            PKMUL(y0.x, ua0.x, uc0.x); PKMUL(y0.y, ua0.y, uc0.y);
            PKMUL(y0.z, ua0.z, uc0.z); PKMUL(y0.w, ua0.w, uc0.w);
            PKMUL(y1.x, ua1.x, uc1.x); PKMUL(y1.y, ua1.y, uc1.y);
            PKMUL(y1.z, ua1.z, uc1.z); PKMUL(y1.w, ua1.w, uc1.w);
#undef PKMUL
            *(uint4*)&Y2[p * YSTR] = y0;
            *(uint4*)&Y2[p * YSTR + 8] = y1;
            lrow[p] = __builtin_bit_cast(unsigned short, __float2half(s));
        }
    }
    __syncthreads();

    // P1: triples, branch-free: x = <Y2[p], emb2[i3]>, write straight to global
#pragma unroll 3
    for (int i = 0; i < 18; ++i) {
        int t = i * 512 + tid;
        if (t < T_) {
            unsigned pk = pkt[i];
            int yb = (int)(pk & 32767u);
            int o3 = (int)(pk >> 15);
            uint4 uy0 = *(const uint4*)&Y2[yb];
            uint4 uy1 = *(const uint4*)&Y2[yb + 8];
            uint4 ue0 = *(const uint4*)&emb2[o3];
            uint4 ue1 = *(const uint4*)&emb2[o3 + 8];
            float s = 0.f;
            s = hdot2(uy0.x, ue0.x, s); s = hdot2(uy0.y, ue0.y, s);
            s = hdot2(uy0.z, ue0.z, s); s = hdot2(uy0.w, ue0.w, s);
            s = hdot2(uy1.x, ue1.x, s); s = hdot2(uy1.y, ue1.y, s);
            s = hdot2(uy1.z, ue1.z, s);
            s = hdot2(uy1.w, ue1.w, s);
            lrow[P_ + t] = __builtin_bit_cast(unsigned short, __float2half(s));
        }
    }
}

// ---------- kernel 2: column partial stats over f16 levels (no atomics) -------------
__global__ __launch_bounds__(256) void stats2_k(const unsigned short* __restrict__ levels,
                                                float* __restrict__ psum,
                                                float* __restrict__ psumsq) {
    int col = blockIdx.x * 256 + threadIdx.x;
    if (col >= NC_) return;
    int sy = blockIdx.y;
    const unsigned short* p = levels + (size_t)(sy * (B_ / NSPLIT)) * LS2 + col;
    float a0 = 0.f, a1 = 0.f, a2 = 0.f, a3 = 0.f;
    float q0 = 0.f, q1 = 0.f, q2 = 0.f, q3 = 0.f;
#pragma unroll 4
    for (int r = 0; r < B_ / NSPLIT; r += 4) {
        float x0 = f16f(p[(size_t)(r + 0) * LS2]);
        float x1 = f16f(p[(size_t)(r + 1) * LS2]);
        float x2 = f16f(p[(size_t)(r + 2) * LS2]);
        float x3 = f16f(p[(size_t)(r + 3) * LS2]);
        a0 += x0; q0 += x0 * x0;
        a1 += x1; q1 += x1 * x1;
        a2 += x2; q2 += x2 * x2;
        a3 += x3; q3 += x3 * x3;
    }
    psum[sy * NC_ + col]   = (a0 + a1) + (a2 + a3);
    psumsq[sy * NC_ + col] = (q0 + q1) + (q2 + q3);
}

// ---------- kernel 3: BN finalize -> per-column scale + scalar C --------------------
__global__ __launch_bounds__(256) void finalize_k(const float* __restrict__ psum,
                                                  const float* __restrict__ psumsq,
                                                  const float* __restrict__ gamma2,
                                                  const float* __restrict__ beta2,
                                                  const float* __restrict__ gw2,
                                                  const float* __restrict__ gamma3,
                                                  const float* __restrict__ beta3,
                                                  const float* __restrict__ gw3,
                                                  float* __restrict__ scale,
                                                  float* __restrict__ Cacc) {
    int col = blockIdx.x * 256 + threadIdx.x;
    float c = 0.f;
    if (col < NC_) {
        float s1 = 0.f, s2 = 0.f;
#pragma unroll
        for (int sy = 0; sy < NSPLIT; ++sy) {
            s1 += psum[sy * NC_ + col];
            s2 += psumsq[sy * NC_ + col];
        }
        float mean = s1 * (1.0f / B_);
        float var  = s2 * (1.0f / B_) - mean * mean;
        float inv  = 1.0f / sqrtf(var + EPS_);
        float g, be, gw;
        if (col < P_) {
            g = gamma2[col]; be = beta2[col]; gw = gw2[col];
        } else {
            int t = col - P_;
            g = gamma3[t]; be = beta3[t]; gw = gw3[t];
        }
        scale[col] = gw * g * inv;
        c = gw * (be - g * inv * mean);
    }
    __shared__ float red[256];
    red[threadIdx.x] = c;
    __syncthreads();
    for (int s = 128; s > 0; s >>= 1) {
        if (threadIdx.x < s) red[threadIdx.x] += red[threadIdx.x + s];
        __syncthreads();
    }
    if (threadIdx.x == 0) atomicAdd(Cacc, red[0]);
}

// ---------- kernel 4: weighted row sum + linear term -> logits ----------------------
__global__ __launch_bounds__(256) void out_k(const unsigned short* __restrict__ levels,
                                             const float* __restrict__ scale,
                                             const int* __restrict__ feats,
                                             const float* __restrict__ w,
                                             const float* __restrict__ Cacc,
                                             const float* __restrict__ bias,
                                             float* __restrict__ out) {
    int b = blockIdx.x, tid = threadIdx.x;
    const uint4* lv = (const uint4*)(levels + (size_t)b * LS2);   // 8 f16 per uint4
    float acc = 0.f;
    // 9880 f16 = 1235 uint4 exactly
    for (int idx = tid; idx < 1235; idx += 256) {
        uint4 u = lv[idx];
        float4 sa = *(const float4*)&scale[idx * 8];
        float4 sb = *(const float4*)&scale[idx * 8 + 4];
        float2 f0 = __half22float2(__builtin_bit_cast(__half2, u.x));
        float2 f1 = __half22float2(__builtin_bit_cast(__half2, u.y));
        float2 f2 = __half22float2(__builtin_bit_cast(__half2, u.z));
        float2 f3 = __half22float2(__builtin_bit_cast(__half2, u.w));
        acc += sa.x * f0.x + sa.y * f0.y + sa.z * f1.x + sa.w * f1.y;
        acc += sb.x * f2.x + sb.y * f2.y + sb.z * f3.x + sb.w * f3.y;
    }
    if (tid < F_) acc += w[feats[b * F_ + tid]];   // linear term
    __shared__ float red[256];
    red[tid] = acc;
    __syncthreads();
    for (int s = 128; s > 0; s >>= 1) {
        if (tid < s) red[tid] += red[tid + s];
        __syncthreads();
    }
    if (tid == 0) out[b] = red[0] + Cacc[0] + bias[0];
}

// ---------- host launcher -----------------------------------------------------------
extern "C" void kernel_launch(void* const* d_in, const int* in_sizes, int n_in,
                              void* d_out, int out_size, void* d_ws, size_t ws_size,
                              hipStream_t stream) {
    const int*   feats  = (const int*)d_in[0];
    const float* w      = (const float*)d_in[1];
    const float* v      = (const float*)d_in[2];
    const float* bias   = (const float*)d_in[3];
    const float* gamma2 = (const float*)d_in[4];
    const float* beta2  = (const float*)d_in[5];
    const float* gw2    = (const float*)d_in[6];
    const float* gamma3 = (const float*)d_in[7];
    const float* beta3  = (const float*)d_in[8];
    const float* gw3    = (const float*)d_in[9];
    const int*   rows   = (const int*)d_in[10];
    const int*   cols   = (const int*)d_in[11];
    const int*   i1     = (const int*)d_in[12];
    const int*   i2     = (const int*)d_in[13];
    const int*   i3     = (const int*)d_in[14];
    float*       out    = (float*)d_out;
    float*       ws     = (float*)d_ws;

    // workspace layout (float offsets)
    float*          scale    = ws;                     // 9880
    float*          psum     = ws + 9880;              // 8*9880 = 79040
    float*          psumsq   = ws + 88920;             // 79040
    float*          Cacc     = ws + 167960;            // 1
    unsigned*       pidx     = (unsigned*)(ws + 168064);        // 9880 u32
    unsigned short* levels   = (unsigned short*)(ws + 177984);  // 1024*9920 f16 (~20.3 MB)

    prep_k<<<(NC_ + 255) / 256, 256, 0, stream>>>(rows, cols, i1, i2, i3, pidx, Cacc);
    levels_k<<<B_, 512, 0, stream>>>(feats, v, pidx, levels);
    stats2_k<<<dim3((NC_ + 255) / 256, NSPLIT), 256, 0, stream>>>(levels, psum, psumsq);
    finalize_k<<<(NC_ + 255) / 256, 256, 0, stream>>>(psum, psumsq,
                                                      gamma2, beta2, gw2,
                                                      gamma3, beta3, gw3, scale, Cacc);
    out_k<<<B_, 256, 0, stream>>>(levels, scale, feats, w, Cacc, bias, out);
}